// Round 4
// baseline (325.288 us; speedup 1.0000x reference)
//
#include <hip/hip_runtime.h>
#include <stdint.h>

// ---------------------------------------------------------------------------
// CommNetActor fused forward v4 — bf16x3 split-precision MFMA (gfx950).
//
//  - 2048 blocks x 512 thr (8 waves); block owns 128 rows (32 batches).
//  - Wave (wr,wc): rows wr*32..+31, cols wc*64..+63. Halved block count
//    halves L2 weight traffic; 4 row-band waves share B via L1.
//  - LDS 67.6 KB (Xhi 32K + Xlo 32K + Pbuf 2K) -> 2 blocks/CU = 16 waves/CU
//    = 4 waves/SIMD (launch_bounds(512,4) caps VGPR at 128).
//  - Comm fused into MFMA space: T = S@W2 = sum_agents(H3@W2); the 4 agent
//    rows of a batch are 4 consecutive acc regs of one lane -> 3 adds. No S
//    buffer, no comm barriers, f32 accumulation.
//  - cl4: two sequential col passes (acc1=H3@W1, acc2=H3@W2 each), results
//    held in regs, written after a single read-complete barrier.
//  - dec: K=512 split 64/wave, partials reduced via LDS atomicAdd (2 KB).
//  - B-streams from L2 into regs, depth-2 prefetch, fully unrolled (%3 rot).
//  - MFMA 32x32x16_bf16, D layout col=lane&31, row=(r&3)+8*(r>>2)+4*(lane>>5).
// ---------------------------------------------------------------------------

typedef __attribute__((ext_vector_type(4)))  float f32x4;
typedef __attribute__((ext_vector_type(16))) float f32x16;
typedef __attribute__((ext_vector_type(8)))  short bf16x8;
typedef __attribute__((ext_vector_type(4)))  short bf16x4;

#define WS_HALF 106496
#define SEG_ENC 0
#define SEG_FC1 8192
#define SEG_FC2 24576
#define SEG_FC3 40960
#define SEG_W1  57344
#define SEG_W2  73728
#define SEG_DEC 90112

#define MFMA(a, b, c) __builtin_amdgcn_mfma_f32_32x32x16_bf16((a), (b), (c), 0, 0, 0)

__device__ __forceinline__ unsigned short bf16_rn(float f) {
  union { float f; uint32_t u; } v; v.f = f;
  uint32_t u = v.u;
  return (unsigned short)((u + 0x7FFFu + ((u >> 16) & 1u)) >> 16);
}
__device__ __forceinline__ float bf16_f32(unsigned short h) {
  union { uint32_t u; float f; } v; v.u = ((uint32_t)h) << 16;
  return v.f;
}
// hi = round-nearest bf16; lo = truncated bf16 of residual.
__device__ __forceinline__ void split_hl(float v, short& h, short& l) {
  unsigned short hh = bf16_rn(v);
  h = (short)hh;
  union { float f; uint32_t u; } c; c.f = v - bf16_f32(hh);
  l = (short)(c.u >> 16);
}
__device__ __forceinline__ f32x16 zero16() {
  f32x16 v;
#pragma unroll
  for (int i = 0; i < 16; ++i) v[i] = 0.0f;
  return v;
}
// swizzled bf16 index: pitch 128, 16B groups XOR'd by row&15
__device__ __forceinline__ int xswz(int row, int g) {
  return row * 128 + ((g ^ (row & 15)) << 3);
}
// barrier draining LDS ops only — register-bound global loads stay in flight
__device__ __forceinline__ void barrier_lds() {
  asm volatile("s_waitcnt lgkmcnt(0)\n\ts_barrier" ::: "memory");
}

// ---------------------------------------------------------------------------
// Weight prep (layout unchanged): fragment f = kc*nbN + nb,
//   value = W[kc*16 + (lane>>5)*8 + j][nb*32 + (lane&31)]
// cl4 split into W1 = Wtop - 0.25*Wbot and W2 = 0.25*Wbot. dec padded N16->32.
// ---------------------------------------------------------------------------
__global__ void prep_weights(const float* __restrict__ enc_w, const float* __restrict__ fc1_w,
                             const float* __restrict__ fc2_w, const float* __restrict__ fc3_w,
                             const float* __restrict__ cl4_w, const float* __restrict__ dec_w,
                             unsigned short* __restrict__ ws) {
  int idx = blockIdx.x * 256 + threadIdx.x;
  if (idx >= WS_HALF) return;
  const float* W; int base, N, nbN, mode;
  if      (idx <  8192) { W = enc_w; base = SEG_ENC; N = 128; nbN = 4; mode = 0; }
  else if (idx < 24576) { W = fc1_w; base = SEG_FC1; N = 128; nbN = 4; mode = 0; }
  else if (idx < 40960) { W = fc2_w; base = SEG_FC2; N = 128; nbN = 4; mode = 0; }
  else if (idx < 57344) { W = fc3_w; base = SEG_FC3; N = 128; nbN = 4; mode = 0; }
  else if (idx < 73728) { W = cl4_w; base = SEG_W1;  N = 128; nbN = 4; mode = 1; }
  else if (idx < 90112) { W = cl4_w; base = SEG_W2;  N = 128; nbN = 4; mode = 2; }
  else                  { W = dec_w; base = SEG_DEC; N = 16;  nbN = 1; mode = 0; }
  int local = idx - base;
  int j    = local & 7;
  int lane = (local >> 3) & 63;
  int frag = local >> 9;
  int nb = frag % nbN;
  int kc = frag / nbN;
  int k = kc * 16 + ((lane >> 5) << 3) + j;
  int n = nb * 32 + (lane & 31);
  float wv;
  if (mode == 0)      wv = (n < N) ? W[k * N + n] : 0.0f;
  else if (mode == 1) wv = W[k * 128 + n] - 0.25f * W[(k + 128) * 128 + n];
  else                wv = 0.25f * W[(k + 128) * 128 + n];
  unsigned short hi = bf16_rn(wv);
  ws[idx]           = hi;
  ws[WS_HALF + idx] = bf16_rn(wv - bf16_f32(hi));
}

// ---------------------------------------------------------------------------
// Standard layer: X[128][K] @ W[K][128] + b, act, in-place into Xhi/Xlo.
// Wave (wr,wc): rows wr*32..+31, cols wc*64..+63 (nb=0,1). B depth-2 prefetch.
// ---------------------------------------------------------------------------
template <int KC, int ACT>
__device__ __forceinline__ void layer_std(short* __restrict__ Xhi, short* __restrict__ Xlo,
                                          const unsigned short* __restrict__ whi,
                                          const unsigned short* __restrict__ wlo,
                                          const float* __restrict__ bias,
                                          int lr, int lh, int wr, int wc) {
  const int l = lh * 32 + lr;
  f32x16 acc0 = zero16(), acc1 = zero16();
  const unsigned short* bh0 = whi + (wc * 2 + 0) * 512 + l * 8;
  const unsigned short* bh1 = whi + (wc * 2 + 1) * 512 + l * 8;
  const unsigned short* bl0 = wlo + (wc * 2 + 0) * 512 + l * 8;
  const unsigned short* bl1 = wlo + (wc * 2 + 1) * 512 + l * 8;
  bf16x8 Bh0[3], Bh1[3], Bl0[3], Bl1[3];
  Bh0[0] = *(const bf16x8*)(bh0);
  Bh1[0] = *(const bf16x8*)(bh1);
  Bl0[0] = *(const bf16x8*)(bl0);
  Bl1[0] = *(const bf16x8*)(bl1);
  Bh0[1] = *(const bf16x8*)(bh0 + 2048);
  Bh1[1] = *(const bf16x8*)(bh1 + 2048);
  Bl0[1] = *(const bf16x8*)(bl0 + 2048);
  Bl1[1] = *(const bf16x8*)(bl1 + 2048);
  barrier_lds();   // X from previous phase visible (B loads stay in flight)
#pragma unroll
  for (int kc = 0; kc < KC; ++kc) {
    const int cur = kc % 3;
    if (kc + 2 < KC) {
      const int nx = (kc + 2) % 3;
      Bh0[nx] = *(const bf16x8*)(bh0 + (kc + 2) * 2048);
      Bh1[nx] = *(const bf16x8*)(bh1 + (kc + 2) * 2048);
      Bl0[nx] = *(const bf16x8*)(bl0 + (kc + 2) * 2048);
      Bl1[nx] = *(const bf16x8*)(bl1 + (kc + 2) * 2048);
    }
    const int xi = xswz(wr * 32 + lr, kc * 2 + lh);
    const bf16x8 ah = *(const bf16x8*)&Xhi[xi];
    const bf16x8 al = *(const bf16x8*)&Xlo[xi];
    acc0 = MFMA(ah, Bh0[cur], acc0);
    acc1 = MFMA(ah, Bh1[cur], acc1);
    acc0 = MFMA(al, Bh0[cur], acc0);
    acc1 = MFMA(al, Bh1[cur], acc1);
    acc0 = MFMA(ah, Bl0[cur], acc0);
    acc1 = MFMA(ah, Bl1[cur], acc1);
  }
  barrier_lds();   // all waves done reading X -> in-place write safe
#pragma unroll
  for (int nb = 0; nb < 2; ++nb) {
    const int col = wc * 64 + nb * 32 + lr;
    const float bv = bias[col];
    const int cg = col >> 3, co = col & 7;
    const f32x16 a = nb ? acc1 : acc0;
#pragma unroll
    for (int r = 0; r < 16; ++r) {
      const int orow = wr * 32 + (r & 3) + 8 * (r >> 2) + 4 * lh;
      float v = a[r] + bv;
      if (ACT == 0)      v = 1.0f / (1.0f + __expf(-v));  // sigmoid
      else if (ACT == 1) v = fmaxf(v, 0.0f);              // relu
      short h, lo2;
      split_hl(v, h, lo2);
      const int idx = orow * 128 + ((cg ^ (orow & 15)) << 3) + co;
      Xhi[idx] = h;
      Xlo[idx] = lo2;
    }
  }
}

// ---------------------------------------------------------------------------
// cl4 pass P (cols wc*64+P*32..+31): acc1 = H3@W1, acc2 = H3@W2.
// Result H4 = acc1[r] + T[r>>2] + b, where T_q = sum of acc2[4q..4q+3]
// (the 4 agent rows of one batch are consecutive accumulator regs).
// ---------------------------------------------------------------------------
template <int P>
__device__ __forceinline__ f32x16 cl4_pass(const short* __restrict__ Xhi,
                                           const short* __restrict__ Xlo,
                                           const unsigned short* __restrict__ whi,
                                           const unsigned short* __restrict__ wlo,
                                           const float* __restrict__ cl4_b,
                                           int lr, int lh, int wr, int wc) {
  const int l = lh * 32 + lr;
  const int cb = wc * 2 + P;
  f32x16 a1 = zero16(), a2 = zero16();
  const unsigned short* b1h = whi + SEG_W1 + cb * 512 + l * 8;
  const unsigned short* b1l = wlo + SEG_W1 + cb * 512 + l * 8;
  const unsigned short* b2h = whi + SEG_W2 + cb * 512 + l * 8;
  const unsigned short* b2l = wlo + SEG_W2 + cb * 512 + l * 8;
  bf16x8 B1h[2], B1l[2], B2h[2], B2l[2];
  B1h[0] = *(const bf16x8*)(b1h);
  B1l[0] = *(const bf16x8*)(b1l);
  B2h[0] = *(const bf16x8*)(b2h);
  B2l[0] = *(const bf16x8*)(b2l);
#pragma unroll
  for (int kc = 0; kc < 8; ++kc) {
    const int cur = kc & 1;
    if (kc < 7) {
      const int nx = cur ^ 1;
      B1h[nx] = *(const bf16x8*)(b1h + (kc + 1) * 2048);
      B1l[nx] = *(const bf16x8*)(b1l + (kc + 1) * 2048);
      B2h[nx] = *(const bf16x8*)(b2h + (kc + 1) * 2048);
      B2l[nx] = *(const bf16x8*)(b2l + (kc + 1) * 2048);
    }
    const int xi = xswz(wr * 32 + lr, kc * 2 + lh);
    const bf16x8 ah = *(const bf16x8*)&Xhi[xi];
    const bf16x8 al = *(const bf16x8*)&Xlo[xi];
    a1 = MFMA(ah, B1h[cur], a1);
    a2 = MFMA(ah, B2h[cur], a2);
    a1 = MFMA(al, B1h[cur], a1);
    a2 = MFMA(al, B2h[cur], a2);
    a1 = MFMA(ah, B1l[cur], a1);
    a2 = MFMA(ah, B2l[cur], a2);
  }
  const int col = wc * 64 + P * 32 + lr;
  const float bv = cl4_b[col];
  f32x16 res;
#pragma unroll
  for (int q = 0; q < 4; ++q) {
    const float T = (a2[4 * q] + a2[4 * q + 1]) + (a2[4 * q + 2] + a2[4 * q + 3]);
#pragma unroll
    for (int rr = 0; rr < 4; ++rr) res[4 * q + rr] = a1[4 * q + rr] + T + bv;
  }
  return res;
}

// ---------------------------------------------------------------------------
__global__ __launch_bounds__(512, 4)
void commnet_fwd(const float* __restrict__ O,
                 const float* __restrict__ enc_b, const float* __restrict__ fc1_b,
                 const float* __restrict__ fc2_b, const float* __restrict__ fc3_b,
                 const float* __restrict__ cl4_b, const float* __restrict__ dec_b,
                 const unsigned short* __restrict__ ws, float* __restrict__ out) {
  __shared__ __attribute__((aligned(16))) short Xhi[128 * 128];  // 32 KB
  __shared__ __attribute__((aligned(16))) short Xlo[128 * 128];  // 32 KB
  __shared__ __attribute__((aligned(16))) float Pbuf[512];       //  2 KB

  const int tid = threadIdx.x;
  const int l = tid & 63, w = tid >> 6;
  const int lr = l & 31, lh = l >> 5;
  const int wr = w >> 1, wc = w & 1;

  Pbuf[tid] = 0.0f;   // dec partial accumulator (one element per thread)

  // ---- stage O [128 x 64] f32 -> split -> swizzled Xhi/Xlo groups 0..7 ----
  {
    const f32x4* Og = (const f32x4*)(O + (long)blockIdx.x * 8192);
#pragma unroll
    for (int it = 0; it < 4; ++it) {
      const int i = it * 512 + tid;       // 0..2047
      const int row = i >> 4;
      const int c4 = (i & 15) << 2;
      f32x4 v = Og[i];
      bf16x4 hv, lv;
#pragma unroll
      for (int j = 0; j < 4; ++j) {
        short hh, ll;
        split_hl(v[j], hh, ll);
        hv[j] = hh; lv[j] = ll;
      }
      const int bi = row * 128 + (((c4 >> 3) ^ (row & 15)) << 3) + (c4 & 7);
      *(bf16x4*)&Xhi[bi] = hv;
      *(bf16x4*)&Xlo[bi] = lv;
    }
  }

  const unsigned short* whi = ws;
  const unsigned short* wlo = ws + WS_HALF;

  layer_std<4, 0>(Xhi, Xlo, whi + SEG_ENC, wlo + SEG_ENC, enc_b, lr, lh, wr, wc);
  layer_std<8, 1>(Xhi, Xlo, whi + SEG_FC1, wlo + SEG_FC1, fc1_b, lr, lh, wr, wc);
  layer_std<8, 1>(Xhi, Xlo, whi + SEG_FC2, wlo + SEG_FC2, fc2_b, lr, lh, wr, wc);
  layer_std<8, 1>(Xhi, Xlo, whi + SEG_FC3, wlo + SEG_FC3, fc3_b, lr, lh, wr, wc);

  // ---- cl4: both passes read H3; results kept in regs; single write phase ----
  barrier_lds();   // H3 (fc3 epilogue) visible
  const f32x16 res0 = cl4_pass<0>(Xhi, Xlo, whi, wlo, cl4_b, lr, lh, wr, wc);
  const f32x16 res1 = cl4_pass<1>(Xhi, Xlo, whi, wlo, cl4_b, lr, lh, wr, wc);
  barrier_lds();   // all H3 reads done -> in-place write safe
#pragma unroll
  for (int p = 0; p < 2; ++p) {
    const int col = wc * 64 + p * 32 + lr;
    const int cg = col >> 3, co = col & 7;
    const f32x16 rs = p ? res1 : res0;
#pragma unroll
    for (int r = 0; r < 16; ++r) {
      const int orow = wr * 32 + (r & 3) + 8 * (r >> 2) + 4 * lh;
      short h, lo2;
      split_hl(rs[r], h, lo2);
      const int idx = orow * 128 + ((cg ^ (orow & 15)) << 3) + co;
      Xhi[idx] = h;
      Xlo[idx] = lo2;
    }
  }

  // ---- dec: [32 x 512] @ dec_w(pad32); K-slice of 64 per wave; LDS atomics ----
  barrier_lds();   // H4 visible (and Pbuf zeros long since visible)
  {
    f32x16 dacc = zero16();
    const unsigned short* bh = whi + SEG_DEC + (w * 4) * 512 + l * 8;
    const unsigned short* bl = wlo + SEG_DEC + (w * 4) * 512 + l * 8;
    bf16x8 Bh[2], Bl[2];
    Bh[0] = *(const bf16x8*)(bh);
    Bl[0] = *(const bf16x8*)(bl);
#pragma unroll
    for (int kq = 0; kq < 4; ++kq) {
      const int cur = kq & 1;
      if (kq < 3) {
        Bh[cur ^ 1] = *(const bf16x8*)(bh + (kq + 1) * 512);
        Bl[cur ^ 1] = *(const bf16x8*)(bl + (kq + 1) * 512);
      }
      const int kcg = w * 4 + kq;          // global k-chunk 0..31
      const int k0 = kcg * 16 + lh * 8;    // 0..504
      const int agent = k0 >> 7;
      const int d0 = k0 & 127;
      const int row = lr * 4 + agent;      // batch lr, agent
      const int xi = xswz(row, d0 >> 3);
      const bf16x8 ah = *(const bf16x8*)&Xhi[xi];
      const bf16x8 al = *(const bf16x8*)&Xlo[xi];
      dacc = MFMA(ah, Bh[cur], dacc);
      dacc = MFMA(al, Bh[cur], dacc);
      dacc = MFMA(ah, Bl[cur], dacc);
    }
    if (lr < 16) {
#pragma unroll
      for (int r = 0; r < 16; ++r) {
        const int batch = (r & 3) + 8 * (r >> 2) + 4 * lh;   // 0..31
        atomicAdd(&Pbuf[batch * 16 + lr], dacc[r]);
      }
    }
  }
  barrier_lds();   // partials complete

  // ---- + bias, softmax over 16 actions, coalesced store ----
  {
    const int c = tid & 15;
    float v = Pbuf[tid] + dec_b[c];
    float m = v;
#pragma unroll
    for (int mk = 1; mk < 16; mk <<= 1) m = fmaxf(m, __shfl_xor(m, mk, 16));
    const float e = __expf(v - m);
    float s = e;
#pragma unroll
    for (int mk = 1; mk < 16; mk <<= 1) s += __shfl_xor(s, mk, 16);
    out[(long)blockIdx.x * 512 + tid] = e / s;
  }
}

// ---------------------------------------------------------------------------
extern "C" void kernel_launch(void* const* d_in, const int* in_sizes, int n_in,
                              void* d_out, int out_size, void* d_ws, size_t ws_size,
                              hipStream_t stream) {
  (void)n_in; (void)out_size; (void)ws_size;  // needs ws_size >= 425,984 B
  const float* O     = (const float*)d_in[0];
  const float* enc_w = (const float*)d_in[1];
  const float* enc_b = (const float*)d_in[2];
  const float* fc1_w = (const float*)d_in[3];
  const float* fc1_b = (const float*)d_in[4];
  const float* fc2_w = (const float*)d_in[5];
  const float* fc2_b = (const float*)d_in[6];
  const float* fc3_w = (const float*)d_in[7];
  const float* fc3_b = (const float*)d_in[8];
  const float* cl4_w = (const float*)d_in[9];
  const float* cl4_b = (const float*)d_in[10];
  const float* dec_w = (const float*)d_in[11];
  const float* dec_b = (const float*)d_in[12];
  unsigned short* wsb = (unsigned short*)d_ws;

  prep_weights<<<(WS_HALF + 255) / 256, 256, 0, stream>>>(enc_w, fc1_w, fc2_w, fc3_w,
                                                          cl4_w, dec_w, wsb);
  const int rows   = in_sizes[0] / 64;   // B*A = 262144
  const int blocks = rows / 128;         // 2048
  commnet_fwd<<<blocks, 512, 0, stream>>>(O, enc_b, fc1_b, fc2_b, fc3_b, cl4_b,
                                          dec_b, wsb, (float*)d_out);
}

// Round 5
// 282.570 us; speedup vs baseline: 1.1512x; 1.1512x over previous
//
#include <hip/hip_runtime.h>
#include <stdint.h>

// ---------------------------------------------------------------------------
// CommNetActor fused forward v5 — bf16x3 split-precision MFMA (gfx950).
//
//  - 4096 blocks x 256 thr (4 waves); block owns 64 rows (16 batches).
//  - Quadrant waves (wr,wc): rows wr*32..+31, cols wc*64..+63. A-dup 2x,
//    B re-read 2x/block (L1-served).
//  - LDS 33 KB (Xhi 16K + Xlo 16K + Pbuf 1K) -> 4 blocks/CU = 16 waves/CU
//    = 4 waves/SIMD; launch_bounds(256,4); register demand ~100 (no spills).
//  - Comm fused into MFMA space: T = sum_agents(H3@W2) from 4 consecutive
//    acc regs of one lane (batch quad) -> 3 adds; no S buffer, no extra sync.
//  - cl4: two sequential col passes (a1=H3@W1, a2=H3@W2), results in regs,
//    single read-complete barrier before in-place write.
//  - dec: K=512 split 8 kc/wave, partials via LDS atomicAdd (1 KB).
//  - B streams L2->regs, depth-2 (kc+1) prefetch; barriers drain lgkmcnt only.
//  - MFMA 32x32x16_bf16, D layout col=lane&31, row=(r&3)+8*(r>>2)+4*(lane>>5).
// ---------------------------------------------------------------------------

typedef __attribute__((ext_vector_type(4)))  float f32x4;
typedef __attribute__((ext_vector_type(16))) float f32x16;
typedef __attribute__((ext_vector_type(8)))  short bf16x8;
typedef __attribute__((ext_vector_type(4)))  short bf16x4;

#define WS_HALF 106496
#define SEG_ENC 0
#define SEG_FC1 8192
#define SEG_FC2 24576
#define SEG_FC3 40960
#define SEG_W1  57344
#define SEG_W2  73728
#define SEG_DEC 90112

#define MFMA(a, b, c) __builtin_amdgcn_mfma_f32_32x32x16_bf16((a), (b), (c), 0, 0, 0)

__device__ __forceinline__ unsigned short bf16_rn(float f) {
  union { float f; uint32_t u; } v; v.f = f;
  uint32_t u = v.u;
  return (unsigned short)((u + 0x7FFFu + ((u >> 16) & 1u)) >> 16);
}
__device__ __forceinline__ float bf16_f32(unsigned short h) {
  union { uint32_t u; float f; } v; v.u = ((uint32_t)h) << 16;
  return v.f;
}
// hi = round-nearest bf16; lo = truncated bf16 of residual.
__device__ __forceinline__ void split_hl(float v, short& h, short& l) {
  unsigned short hh = bf16_rn(v);
  h = (short)hh;
  union { float f; uint32_t u; } c; c.f = v - bf16_f32(hh);
  l = (short)(c.u >> 16);
}
__device__ __forceinline__ f32x16 zero16() {
  f32x16 v;
#pragma unroll
  for (int i = 0; i < 16; ++i) v[i] = 0.0f;
  return v;
}
// swizzled bf16 index: pitch 128, 16B groups XOR'd by row&15 (<=2-way = free)
__device__ __forceinline__ int xswz(int row, int g) {
  return row * 128 + ((g ^ (row & 15)) << 3);
}
// barrier draining LDS ops only — register-bound global loads stay in flight
__device__ __forceinline__ void barrier_lds() {
  asm volatile("s_waitcnt lgkmcnt(0)\n\ts_barrier" ::: "memory");
}

// ---------------------------------------------------------------------------
// Weight prep (layout unchanged): fragment f = kc*nbN + nb,
//   value = W[kc*16 + (lane>>5)*8 + j][nb*32 + (lane&31)]
// cl4 split into W1 = Wtop - 0.25*Wbot and W2 = 0.25*Wbot. dec padded N16->32.
// ---------------------------------------------------------------------------
__global__ void prep_weights(const float* __restrict__ enc_w, const float* __restrict__ fc1_w,
                             const float* __restrict__ fc2_w, const float* __restrict__ fc3_w,
                             const float* __restrict__ cl4_w, const float* __restrict__ dec_w,
                             unsigned short* __restrict__ ws) {
  int idx = blockIdx.x * 256 + threadIdx.x;
  if (idx >= WS_HALF) return;
  const float* W; int base, N, nbN, mode;
  if      (idx <  8192) { W = enc_w; base = SEG_ENC; N = 128; nbN = 4; mode = 0; }
  else if (idx < 24576) { W = fc1_w; base = SEG_FC1; N = 128; nbN = 4; mode = 0; }
  else if (idx < 40960) { W = fc2_w; base = SEG_FC2; N = 128; nbN = 4; mode = 0; }
  else if (idx < 57344) { W = fc3_w; base = SEG_FC3; N = 128; nbN = 4; mode = 0; }
  else if (idx < 73728) { W = cl4_w; base = SEG_W1;  N = 128; nbN = 4; mode = 1; }
  else if (idx < 90112) { W = cl4_w; base = SEG_W2;  N = 128; nbN = 4; mode = 2; }
  else                  { W = dec_w; base = SEG_DEC; N = 16;  nbN = 1; mode = 0; }
  int local = idx - base;
  int j    = local & 7;
  int lane = (local >> 3) & 63;
  int frag = local >> 9;
  int nb = frag % nbN;
  int kc = frag / nbN;
  int k = kc * 16 + ((lane >> 5) << 3) + j;
  int n = nb * 32 + (lane & 31);
  float wv;
  if (mode == 0)      wv = (n < N) ? W[k * N + n] : 0.0f;
  else if (mode == 1) wv = W[k * 128 + n] - 0.25f * W[(k + 128) * 128 + n];
  else                wv = 0.25f * W[(k + 128) * 128 + n];
  unsigned short hi = bf16_rn(wv);
  ws[idx]           = hi;
  ws[WS_HALF + idx] = bf16_rn(wv - bf16_f32(hi));
}

// ---------------------------------------------------------------------------
// Standard layer: X[64][K] @ W[K][128] + b, act, in-place into Xhi/Xlo.
// Wave (wr,wc): rows wr*32..+31, cols wc*64..+63 (nb=0,1). Depth-2 B prefetch.
// ---------------------------------------------------------------------------
template <int KC, int ACT>
__device__ __forceinline__ void layer_std(short* __restrict__ Xhi, short* __restrict__ Xlo,
                                          const unsigned short* __restrict__ whi,
                                          const unsigned short* __restrict__ wlo,
                                          const float* __restrict__ bias,
                                          int lr, int lh, int wr, int wc) {
  const int l = lh * 32 + lr;
  f32x16 acc0 = zero16(), acc1 = zero16();
  const unsigned short* bh0 = whi + (wc * 2 + 0) * 512 + l * 8;
  const unsigned short* bh1 = whi + (wc * 2 + 1) * 512 + l * 8;
  const unsigned short* bl0 = wlo + (wc * 2 + 0) * 512 + l * 8;
  const unsigned short* bl1 = wlo + (wc * 2 + 1) * 512 + l * 8;
  bf16x8 Bh0[2], Bh1[2], Bl0[2], Bl1[2];
  Bh0[0] = *(const bf16x8*)(bh0);
  Bh1[0] = *(const bf16x8*)(bh1);
  Bl0[0] = *(const bf16x8*)(bl0);
  Bl1[0] = *(const bf16x8*)(bl1);
  barrier_lds();   // X from previous phase visible (B loads stay in flight)
#pragma unroll
  for (int kc = 0; kc < KC; ++kc) {
    const int cur = kc & 1;
    if (kc + 1 < KC) {
      const int nx = cur ^ 1;
      Bh0[nx] = *(const bf16x8*)(bh0 + (kc + 1) * 2048);
      Bh1[nx] = *(const bf16x8*)(bh1 + (kc + 1) * 2048);
      Bl0[nx] = *(const bf16x8*)(bl0 + (kc + 1) * 2048);
      Bl1[nx] = *(const bf16x8*)(bl1 + (kc + 1) * 2048);
    }
    const int xi = xswz(wr * 32 + lr, kc * 2 + lh);
    const bf16x8 ah = *(const bf16x8*)&Xhi[xi];
    const bf16x8 al = *(const bf16x8*)&Xlo[xi];
    acc0 = MFMA(ah, Bh0[cur], acc0);
    acc1 = MFMA(ah, Bh1[cur], acc1);
    acc0 = MFMA(al, Bh0[cur], acc0);
    acc1 = MFMA(al, Bh1[cur], acc1);
    acc0 = MFMA(ah, Bl0[cur], acc0);
    acc1 = MFMA(ah, Bl1[cur], acc1);
  }
  barrier_lds();   // all waves done reading X -> in-place write safe
#pragma unroll
  for (int nb = 0; nb < 2; ++nb) {
    const int col = wc * 64 + nb * 32 + lr;
    const float bv = bias[col];
    const int cg = col >> 3, co = col & 7;
    const f32x16 a = nb ? acc1 : acc0;
#pragma unroll
    for (int r = 0; r < 16; ++r) {
      const int orow = wr * 32 + (r & 3) + 8 * (r >> 2) + 4 * lh;
      float v = a[r] + bv;
      if (ACT == 0)      v = 1.0f / (1.0f + __expf(-v));  // sigmoid
      else if (ACT == 1) v = fmaxf(v, 0.0f);              // relu
      short h, lo2;
      split_hl(v, h, lo2);
      const int idx = orow * 128 + ((cg ^ (orow & 15)) << 3) + co;
      Xhi[idx] = h;
      Xlo[idx] = lo2;
    }
  }
}

// ---------------------------------------------------------------------------
// cl4 pass P (cols wc*64+P*32..+31): a1 = H3@W1, a2 = H3@W2.
// H4 = a1[r] + T_q + b, where T_q = sum of a2[4q..4q+3] (the 4 agent rows of
// one batch sit in 4 consecutive accumulator regs of the same lane).
// ---------------------------------------------------------------------------
template <int P>
__device__ __forceinline__ f32x16 cl4_pass(const short* __restrict__ Xhi,
                                           const short* __restrict__ Xlo,
                                           const unsigned short* __restrict__ whi,
                                           const unsigned short* __restrict__ wlo,
                                           const float* __restrict__ cl4_b,
                                           int lr, int lh, int wr, int wc) {
  const int l = lh * 32 + lr;
  const int cb = wc * 2 + P;
  f32x16 a1 = zero16(), a2 = zero16();
  const unsigned short* b1h = whi + SEG_W1 + cb * 512 + l * 8;
  const unsigned short* b1l = wlo + SEG_W1 + cb * 512 + l * 8;
  const unsigned short* b2h = whi + SEG_W2 + cb * 512 + l * 8;
  const unsigned short* b2l = wlo + SEG_W2 + cb * 512 + l * 8;
  bf16x8 B1h[2], B1l[2], B2h[2], B2l[2];
  B1h[0] = *(const bf16x8*)(b1h);
  B1l[0] = *(const bf16x8*)(b1l);
  B2h[0] = *(const bf16x8*)(b2h);
  B2l[0] = *(const bf16x8*)(b2l);
#pragma unroll
  for (int kc = 0; kc < 8; ++kc) {
    const int cur = kc & 1;
    if (kc < 7) {
      const int nx = cur ^ 1;
      B1h[nx] = *(const bf16x8*)(b1h + (kc + 1) * 2048);
      B1l[nx] = *(const bf16x8*)(b1l + (kc + 1) * 2048);
      B2h[nx] = *(const bf16x8*)(b2h + (kc + 1) * 2048);
      B2l[nx] = *(const bf16x8*)(b2l + (kc + 1) * 2048);
    }
    const int xi = xswz(wr * 32 + lr, kc * 2 + lh);
    const bf16x8 ah = *(const bf16x8*)&Xhi[xi];
    const bf16x8 al = *(const bf16x8*)&Xlo[xi];
    a1 = MFMA(ah, B1h[cur], a1);
    a2 = MFMA(ah, B2h[cur], a2);
    a1 = MFMA(al, B1h[cur], a1);
    a2 = MFMA(al, B2h[cur], a2);
    a1 = MFMA(ah, B1l[cur], a1);
    a2 = MFMA(ah, B2l[cur], a2);
  }
  const int col = wc * 64 + P * 32 + lr;
  const float bv = cl4_b[col];
  f32x16 res;
#pragma unroll
  for (int q = 0; q < 4; ++q) {
    const float T = (a2[4 * q] + a2[4 * q + 1]) + (a2[4 * q + 2] + a2[4 * q + 3]);
#pragma unroll
    for (int rr = 0; rr < 4; ++rr) res[4 * q + rr] = a1[4 * q + rr] + T + bv;
  }
  return res;
}

// ---------------------------------------------------------------------------
__global__ __launch_bounds__(256, 4)
void commnet_fwd(const float* __restrict__ O,
                 const float* __restrict__ enc_b, const float* __restrict__ fc1_b,
                 const float* __restrict__ fc2_b, const float* __restrict__ fc3_b,
                 const float* __restrict__ cl4_b, const float* __restrict__ dec_b,
                 const unsigned short* __restrict__ ws, float* __restrict__ out) {
  __shared__ __attribute__((aligned(16))) short Xhi[64 * 128];  // 16 KB
  __shared__ __attribute__((aligned(16))) short Xlo[64 * 128];  // 16 KB
  __shared__ __attribute__((aligned(16))) float Pbuf[256];      //  1 KB

  const int tid = threadIdx.x;
  const int l = tid & 63, w = tid >> 6;
  const int lr = l & 31, lh = l >> 5;
  const int wr = w >> 1, wc = w & 1;

  Pbuf[tid] = 0.0f;   // dec partial accumulator (one element per thread)

  // ---- stage O [64 x 64] f32 -> split -> swizzled Xhi/Xlo groups 0..7 ----
  {
    const f32x4* Og = (const f32x4*)(O + (long)blockIdx.x * 4096);
#pragma unroll
    for (int it = 0; it < 4; ++it) {
      const int i = it * 256 + tid;       // 0..1023
      const int row = i >> 4;
      const int c4 = (i & 15) << 2;
      f32x4 v = Og[i];
      bf16x4 hv, lv;
#pragma unroll
      for (int j = 0; j < 4; ++j) {
        short hh, ll;
        split_hl(v[j], hh, ll);
        hv[j] = hh; lv[j] = ll;
      }
      const int bi = row * 128 + (((c4 >> 3) ^ (row & 15)) << 3) + (c4 & 7);
      *(bf16x4*)&Xhi[bi] = hv;
      *(bf16x4*)&Xlo[bi] = lv;
    }
  }

  const unsigned short* whi = ws;
  const unsigned short* wlo = ws + WS_HALF;

  layer_std<4, 0>(Xhi, Xlo, whi + SEG_ENC, wlo + SEG_ENC, enc_b, lr, lh, wr, wc);
  layer_std<8, 1>(Xhi, Xlo, whi + SEG_FC1, wlo + SEG_FC1, fc1_b, lr, lh, wr, wc);
  layer_std<8, 1>(Xhi, Xlo, whi + SEG_FC2, wlo + SEG_FC2, fc2_b, lr, lh, wr, wc);
  layer_std<8, 1>(Xhi, Xlo, whi + SEG_FC3, wlo + SEG_FC3, fc3_b, lr, lh, wr, wc);

  // ---- cl4: both passes read H3; results kept in regs; single write phase ----
  barrier_lds();   // H3 (fc3 epilogue) visible
  const f32x16 res0 = cl4_pass<0>(Xhi, Xlo, whi, wlo, cl4_b, lr, lh, wr, wc);
  const f32x16 res1 = cl4_pass<1>(Xhi, Xlo, whi, wlo, cl4_b, lr, lh, wr, wc);
  barrier_lds();   // all H3 reads done -> in-place write safe
#pragma unroll
  for (int p = 0; p < 2; ++p) {
    const int col = wc * 64 + p * 32 + lr;
    const int cg = col >> 3, co = col & 7;
    const f32x16 rs = p ? res1 : res0;
#pragma unroll
    for (int r = 0; r < 16; ++r) {
      const int orow = wr * 32 + (r & 3) + 8 * (r >> 2) + 4 * lh;
      short h, lo2;
      split_hl(rs[r], h, lo2);
      const int idx = orow * 128 + ((cg ^ (orow & 15)) << 3) + co;
      Xhi[idx] = h;
      Xlo[idx] = lo2;
    }
  }

  // ---- dec: [16 x 512] @ dec_w(pad32); 8 kc per wave; LDS atomic reduce ----
  barrier_lds();   // H4 visible
  {
    f32x16 dacc = zero16();
    const unsigned short* bh = whi + SEG_DEC + (w * 8) * 512 + l * 8;
    const unsigned short* bl = wlo + SEG_DEC + (w * 8) * 512 + l * 8;
    bf16x8 Bh[2], Bl[2];
    Bh[0] = *(const bf16x8*)(bh);
    Bl[0] = *(const bf16x8*)(bl);
#pragma unroll
    for (int kq = 0; kq < 8; ++kq) {
      const int cur = kq & 1;
      if (kq < 7) {
        Bh[cur ^ 1] = *(const bf16x8*)(bh + (kq + 1) * 512);
        Bl[cur ^ 1] = *(const bf16x8*)(bl + (kq + 1) * 512);
      }
      const int kcg = w * 8 + kq;          // global k-chunk 0..31
      const int k0 = kcg * 16 + lh * 8;    // 0..504
      const int agent = k0 >> 7;
      const int d0 = k0 & 127;
      const int row = (lr & 15) * 4 + agent;   // batch (dup for lr>=16), agent
      const int xi = xswz(row, d0 >> 3);
      const bf16x8 ah = *(const bf16x8*)&Xhi[xi];
      const bf16x8 al = *(const bf16x8*)&Xlo[xi];
      dacc = MFMA(ah, Bh[cur], dacc);
      dacc = MFMA(al, Bh[cur], dacc);
      dacc = MFMA(ah, Bl[cur], dacc);
    }
    if (lr < 16) {   // cols 16..31 are zero-pad; D rows 16..31 are dup batches
#pragma unroll
      for (int r = 0; r < 8; ++r) {
        const int batch = (r & 3) + 8 * (r >> 2) + 4 * lh;   // 0..15
        atomicAdd(&Pbuf[batch * 16 + lr], dacc[r]);
      }
    }
  }
  barrier_lds();   // partials complete

  // ---- + bias, softmax over 16 actions, coalesced store ----
  {
    const int c = tid & 15;
    float v = Pbuf[tid] + dec_b[c];
    float m = v;
#pragma unroll
    for (int mk = 1; mk < 16; mk <<= 1) m = fmaxf(m, __shfl_xor(m, mk, 16));
    const float e = __expf(v - m);
    float s = e;
#pragma unroll
    for (int mk = 1; mk < 16; mk <<= 1) s += __shfl_xor(s, mk, 16);
    out[(long)blockIdx.x * 256 + tid] = e / s;
  }
}

// ---------------------------------------------------------------------------
extern "C" void kernel_launch(void* const* d_in, const int* in_sizes, int n_in,
                              void* d_out, int out_size, void* d_ws, size_t ws_size,
                              hipStream_t stream) {
  (void)n_in; (void)out_size; (void)ws_size;  // needs ws_size >= 425,984 B
  const float* O     = (const float*)d_in[0];
  const float* enc_w = (const float*)d_in[1];
  const float* enc_b = (const float*)d_in[2];
  const float* fc1_w = (const float*)d_in[3];
  const float* fc1_b = (const float*)d_in[4];
  const float* fc2_w = (const float*)d_in[5];
  const float* fc2_b = (const float*)d_in[6];
  const float* fc3_w = (const float*)d_in[7];
  const float* fc3_b = (const float*)d_in[8];
  const float* cl4_w = (const float*)d_in[9];
  const float* cl4_b = (const float*)d_in[10];
  const float* dec_w = (const float*)d_in[11];
  const float* dec_b = (const float*)d_in[12];
  unsigned short* wsb = (unsigned short*)d_ws;

  prep_weights<<<(WS_HALF + 255) / 256, 256, 0, stream>>>(enc_w, fc1_w, fc2_w, fc3_w,
                                                          cl4_w, dec_w, wsb);
  const int rows   = in_sizes[0] / 64;   // B*A = 262144
  const int blocks = rows / 64;          // 4096
  commnet_fwd<<<blocks, 256, 0, stream>>>(O, enc_b, fc1_b, fc2_b, fc3_b, cl4_b,
                                          dec_b, wsb, (float*)d_out);
}

// Round 6
// 217.483 us; speedup vs baseline: 1.4957x; 1.2993x over previous
//
#include <hip/hip_runtime.h>
#include <stdint.h>

// ---------------------------------------------------------------------------
// CommNetActor fused forward v6 — bf16x3 split-precision MFMA (gfx950).
//
//  v5 with ONE change: __launch_bounds__(256, 3) instead of (256, 4).
//  Rationale (R5 post-mortem): at 4 waves/SIMD the unified VGPR budget is
//  128/wave; the compiler splits 64 arch + 64 acc and the K-loop working set
//  (~100 arch) spills to scratch (209 MB WRITE_SIZE, 100+ MB extra FETCH).
//  At 3 waves/SIMD the budget is 170/wave (~120 arch + 50 acc) which fits the
//  counted demand (cl4 peak: 32 B-bufs + 8 A-frags + ptrs + res0 held, 48 acc).
//  Residency: LDS 33.8 KB allows 4 blocks/CU -> register-limited at exactly
//  3 blocks/CU = 12 waves/CU, no spills.
//
//  - 4096 blocks x 256 thr (4 waves); block owns 64 rows (16 batches).
//  - Quadrant waves (wr,wc): rows wr*32..+31, cols wc*64..+63. A-dup 2x.
//  - Comm fused into MFMA space: T = sum_agents(H3@W2) from 4 consecutive
//    acc regs of one lane (batch quad) -> 3 adds; no S buffer.
//  - cl4: two sequential col passes (a1=H3@W1, a2=H3@W2), results in regs,
//    single read-complete barrier before in-place write.
//  - dec: K=512 split 8 kc/wave, partials via LDS atomicAdd (1 KB).
//  - B streams L2->regs, depth-2 (kc+1) prefetch; barriers drain lgkmcnt only.
//  - MFMA 32x32x16_bf16, D layout col=lane&31, row=(r&3)+8*(r>>2)+4*(lane>>5).
// ---------------------------------------------------------------------------

typedef __attribute__((ext_vector_type(4)))  float f32x4;
typedef __attribute__((ext_vector_type(16))) float f32x16;
typedef __attribute__((ext_vector_type(8)))  short bf16x8;
typedef __attribute__((ext_vector_type(4)))  short bf16x4;

#define WS_HALF 106496
#define SEG_ENC 0
#define SEG_FC1 8192
#define SEG_FC2 24576
#define SEG_FC3 40960
#define SEG_W1  57344
#define SEG_W2  73728
#define SEG_DEC 90112

#define MFMA(a, b, c) __builtin_amdgcn_mfma_f32_32x32x16_bf16((a), (b), (c), 0, 0, 0)

__device__ __forceinline__ unsigned short bf16_rn(float f) {
  union { float f; uint32_t u; } v; v.f = f;
  uint32_t u = v.u;
  return (unsigned short)((u + 0x7FFFu + ((u >> 16) & 1u)) >> 16);
}
__device__ __forceinline__ float bf16_f32(unsigned short h) {
  union { uint32_t u; float f; } v; v.u = ((uint32_t)h) << 16;
  return v.f;
}
// hi = round-nearest bf16; lo = truncated bf16 of residual.
__device__ __forceinline__ void split_hl(float v, short& h, short& l) {
  unsigned short hh = bf16_rn(v);
  h = (short)hh;
  union { float f; uint32_t u; } c; c.f = v - bf16_f32(hh);
  l = (short)(c.u >> 16);
}
__device__ __forceinline__ f32x16 zero16() {
  f32x16 v;
#pragma unroll
  for (int i = 0; i < 16; ++i) v[i] = 0.0f;
  return v;
}
// swizzled bf16 index: pitch 128, 16B groups XOR'd by row&15 (<=2-way = free)
__device__ __forceinline__ int xswz(int row, int g) {
  return row * 128 + ((g ^ (row & 15)) << 3);
}
// barrier draining LDS ops only — register-bound global loads stay in flight
__device__ __forceinline__ void barrier_lds() {
  asm volatile("s_waitcnt lgkmcnt(0)\n\ts_barrier" ::: "memory");
}

// ---------------------------------------------------------------------------
// Weight prep (layout unchanged): fragment f = kc*nbN + nb,
//   value = W[kc*16 + (lane>>5)*8 + j][nb*32 + (lane&31)]
// cl4 split into W1 = Wtop - 0.25*Wbot and W2 = 0.25*Wbot. dec padded N16->32.
// ---------------------------------------------------------------------------
__global__ void prep_weights(const float* __restrict__ enc_w, const float* __restrict__ fc1_w,
                             const float* __restrict__ fc2_w, const float* __restrict__ fc3_w,
                             const float* __restrict__ cl4_w, const float* __restrict__ dec_w,
                             unsigned short* __restrict__ ws) {
  int idx = blockIdx.x * 256 + threadIdx.x;
  if (idx >= WS_HALF) return;
  const float* W; int base, N, nbN, mode;
  if      (idx <  8192) { W = enc_w; base = SEG_ENC; N = 128; nbN = 4; mode = 0; }
  else if (idx < 24576) { W = fc1_w; base = SEG_FC1; N = 128; nbN = 4; mode = 0; }
  else if (idx < 40960) { W = fc2_w; base = SEG_FC2; N = 128; nbN = 4; mode = 0; }
  else if (idx < 57344) { W = fc3_w; base = SEG_FC3; N = 128; nbN = 4; mode = 0; }
  else if (idx < 73728) { W = cl4_w; base = SEG_W1;  N = 128; nbN = 4; mode = 1; }
  else if (idx < 90112) { W = cl4_w; base = SEG_W2;  N = 128; nbN = 4; mode = 2; }
  else                  { W = dec_w; base = SEG_DEC; N = 16;  nbN = 1; mode = 0; }
  int local = idx - base;
  int j    = local & 7;
  int lane = (local >> 3) & 63;
  int frag = local >> 9;
  int nb = frag % nbN;
  int kc = frag / nbN;
  int k = kc * 16 + ((lane >> 5) << 3) + j;
  int n = nb * 32 + (lane & 31);
  float wv;
  if (mode == 0)      wv = (n < N) ? W[k * N + n] : 0.0f;
  else if (mode == 1) wv = W[k * 128 + n] - 0.25f * W[(k + 128) * 128 + n];
  else                wv = 0.25f * W[(k + 128) * 128 + n];
  unsigned short hi = bf16_rn(wv);
  ws[idx]           = hi;
  ws[WS_HALF + idx] = bf16_rn(wv - bf16_f32(hi));
}

// ---------------------------------------------------------------------------
// Standard layer: X[64][K] @ W[K][128] + b, act, in-place into Xhi/Xlo.
// Wave (wr,wc): rows wr*32..+31, cols wc*64..+63 (nb=0,1). Depth-2 B prefetch.
// ---------------------------------------------------------------------------
template <int KC, int ACT>
__device__ __forceinline__ void layer_std(short* __restrict__ Xhi, short* __restrict__ Xlo,
                                          const unsigned short* __restrict__ whi,
                                          const unsigned short* __restrict__ wlo,
                                          const float* __restrict__ bias,
                                          int lr, int lh, int wr, int wc) {
  const int l = lh * 32 + lr;
  f32x16 acc0 = zero16(), acc1 = zero16();
  const unsigned short* bh0 = whi + (wc * 2 + 0) * 512 + l * 8;
  const unsigned short* bh1 = whi + (wc * 2 + 1) * 512 + l * 8;
  const unsigned short* bl0 = wlo + (wc * 2 + 0) * 512 + l * 8;
  const unsigned short* bl1 = wlo + (wc * 2 + 1) * 512 + l * 8;
  bf16x8 Bh0[2], Bh1[2], Bl0[2], Bl1[2];
  Bh0[0] = *(const bf16x8*)(bh0);
  Bh1[0] = *(const bf16x8*)(bh1);
  Bl0[0] = *(const bf16x8*)(bl0);
  Bl1[0] = *(const bf16x8*)(bl1);
  barrier_lds();   // X from previous phase visible (B loads stay in flight)
#pragma unroll
  for (int kc = 0; kc < KC; ++kc) {
    const int cur = kc & 1;
    if (kc + 1 < KC) {
      const int nx = cur ^ 1;
      Bh0[nx] = *(const bf16x8*)(bh0 + (kc + 1) * 2048);
      Bh1[nx] = *(const bf16x8*)(bh1 + (kc + 1) * 2048);
      Bl0[nx] = *(const bf16x8*)(bl0 + (kc + 1) * 2048);
      Bl1[nx] = *(const bf16x8*)(bl1 + (kc + 1) * 2048);
    }
    const int xi = xswz(wr * 32 + lr, kc * 2 + lh);
    const bf16x8 ah = *(const bf16x8*)&Xhi[xi];
    const bf16x8 al = *(const bf16x8*)&Xlo[xi];
    acc0 = MFMA(ah, Bh0[cur], acc0);
    acc1 = MFMA(ah, Bh1[cur], acc1);
    acc0 = MFMA(al, Bh0[cur], acc0);
    acc1 = MFMA(al, Bh1[cur], acc1);
    acc0 = MFMA(ah, Bl0[cur], acc0);
    acc1 = MFMA(ah, Bl1[cur], acc1);
  }
  barrier_lds();   // all waves done reading X -> in-place write safe
#pragma unroll
  for (int nb = 0; nb < 2; ++nb) {
    const int col = wc * 64 + nb * 32 + lr;
    const float bv = bias[col];
    const int cg = col >> 3, co = col & 7;
    const f32x16 a = nb ? acc1 : acc0;
#pragma unroll
    for (int r = 0; r < 16; ++r) {
      const int orow = wr * 32 + (r & 3) + 8 * (r >> 2) + 4 * lh;
      float v = a[r] + bv;
      if (ACT == 0)      v = 1.0f / (1.0f + __expf(-v));  // sigmoid
      else if (ACT == 1) v = fmaxf(v, 0.0f);              // relu
      short h, lo2;
      split_hl(v, h, lo2);
      const int idx = orow * 128 + ((cg ^ (orow & 15)) << 3) + co;
      Xhi[idx] = h;
      Xlo[idx] = lo2;
    }
  }
}

// ---------------------------------------------------------------------------
// cl4 pass P (cols wc*64+P*32..+31): a1 = H3@W1, a2 = H3@W2.
// H4 = a1[r] + T_q + b, where T_q = sum of a2[4q..4q+3] (the 4 agent rows of
// one batch sit in 4 consecutive accumulator regs of the same lane).
// ---------------------------------------------------------------------------
template <int P>
__device__ __forceinline__ f32x16 cl4_pass(const short* __restrict__ Xhi,
                                           const short* __restrict__ Xlo,
                                           const unsigned short* __restrict__ whi,
                                           const unsigned short* __restrict__ wlo,
                                           const float* __restrict__ cl4_b,
                                           int lr, int lh, int wr, int wc) {
  const int l = lh * 32 + lr;
  const int cb = wc * 2 + P;
  f32x16 a1 = zero16(), a2 = zero16();
  const unsigned short* b1h = whi + SEG_W1 + cb * 512 + l * 8;
  const unsigned short* b1l = wlo + SEG_W1 + cb * 512 + l * 8;
  const unsigned short* b2h = whi + SEG_W2 + cb * 512 + l * 8;
  const unsigned short* b2l = wlo + SEG_W2 + cb * 512 + l * 8;
  bf16x8 B1h[2], B1l[2], B2h[2], B2l[2];
  B1h[0] = *(const bf16x8*)(b1h);
  B1l[0] = *(const bf16x8*)(b1l);
  B2h[0] = *(const bf16x8*)(b2h);
  B2l[0] = *(const bf16x8*)(b2l);
#pragma unroll
  for (int kc = 0; kc < 8; ++kc) {
    const int cur = kc & 1;
    if (kc < 7) {
      const int nx = cur ^ 1;
      B1h[nx] = *(const bf16x8*)(b1h + (kc + 1) * 2048);
      B1l[nx] = *(const bf16x8*)(b1l + (kc + 1) * 2048);
      B2h[nx] = *(const bf16x8*)(b2h + (kc + 1) * 2048);
      B2l[nx] = *(const bf16x8*)(b2l + (kc + 1) * 2048);
    }
    const int xi = xswz(wr * 32 + lr, kc * 2 + lh);
    const bf16x8 ah = *(const bf16x8*)&Xhi[xi];
    const bf16x8 al = *(const bf16x8*)&Xlo[xi];
    a1 = MFMA(ah, B1h[cur], a1);
    a2 = MFMA(ah, B2h[cur], a2);
    a1 = MFMA(al, B1h[cur], a1);
    a2 = MFMA(al, B2h[cur], a2);
    a1 = MFMA(ah, B1l[cur], a1);
    a2 = MFMA(ah, B2l[cur], a2);
  }
  const int col = wc * 64 + P * 32 + lr;
  const float bv = cl4_b[col];
  f32x16 res;
#pragma unroll
  for (int q = 0; q < 4; ++q) {
    const float T = (a2[4 * q] + a2[4 * q + 1]) + (a2[4 * q + 2] + a2[4 * q + 3]);
#pragma unroll
    for (int rr = 0; rr < 4; ++rr) res[4 * q + rr] = a1[4 * q + rr] + T + bv;
  }
  return res;
}

// ---------------------------------------------------------------------------
__global__ __launch_bounds__(256, 3)
void commnet_fwd(const float* __restrict__ O,
                 const float* __restrict__ enc_b, const float* __restrict__ fc1_b,
                 const float* __restrict__ fc2_b, const float* __restrict__ fc3_b,
                 const float* __restrict__ cl4_b, const float* __restrict__ dec_b,
                 const unsigned short* __restrict__ ws, float* __restrict__ out) {
  __shared__ __attribute__((aligned(16))) short Xhi[64 * 128];  // 16 KB
  __shared__ __attribute__((aligned(16))) short Xlo[64 * 128];  // 16 KB
  __shared__ __attribute__((aligned(16))) float Pbuf[256];      //  1 KB

  const int tid = threadIdx.x;
  const int l = tid & 63, w = tid >> 6;
  const int lr = l & 31, lh = l >> 5;
  const int wr = w >> 1, wc = w & 1;

  Pbuf[tid] = 0.0f;   // dec partial accumulator (one element per thread)

  // ---- stage O [64 x 64] f32 -> split -> swizzled Xhi/Xlo groups 0..7 ----
  {
    const f32x4* Og = (const f32x4*)(O + (long)blockIdx.x * 4096);
#pragma unroll
    for (int it = 0; it < 4; ++it) {
      const int i = it * 256 + tid;       // 0..1023
      const int row = i >> 4;
      const int c4 = (i & 15) << 2;
      f32x4 v = Og[i];
      bf16x4 hv, lv;
#pragma unroll
      for (int j = 0; j < 4; ++j) {
        short hh, ll;
        split_hl(v[j], hh, ll);
        hv[j] = hh; lv[j] = ll;
      }
      const int bi = row * 128 + (((c4 >> 3) ^ (row & 15)) << 3) + (c4 & 7);
      *(bf16x4*)&Xhi[bi] = hv;
      *(bf16x4*)&Xlo[bi] = lv;
    }
  }

  const unsigned short* whi = ws;
  const unsigned short* wlo = ws + WS_HALF;

  layer_std<4, 0>(Xhi, Xlo, whi + SEG_ENC, wlo + SEG_ENC, enc_b, lr, lh, wr, wc);
  layer_std<8, 1>(Xhi, Xlo, whi + SEG_FC1, wlo + SEG_FC1, fc1_b, lr, lh, wr, wc);
  layer_std<8, 1>(Xhi, Xlo, whi + SEG_FC2, wlo + SEG_FC2, fc2_b, lr, lh, wr, wc);
  layer_std<8, 1>(Xhi, Xlo, whi + SEG_FC3, wlo + SEG_FC3, fc3_b, lr, lh, wr, wc);

  // ---- cl4: both passes read H3; results kept in regs; single write phase ----
  barrier_lds();   // H3 (fc3 epilogue) visible
  const f32x16 res0 = cl4_pass<0>(Xhi, Xlo, whi, wlo, cl4_b, lr, lh, wr, wc);
  const f32x16 res1 = cl4_pass<1>(Xhi, Xlo, whi, wlo, cl4_b, lr, lh, wr, wc);
  barrier_lds();   // all H3 reads done -> in-place write safe
#pragma unroll
  for (int p = 0; p < 2; ++p) {
    const int col = wc * 64 + p * 32 + lr;
    const int cg = col >> 3, co = col & 7;
    const f32x16 rs = p ? res1 : res0;
#pragma unroll
    for (int r = 0; r < 16; ++r) {
      const int orow = wr * 32 + (r & 3) + 8 * (r >> 2) + 4 * lh;
      short h, lo2;
      split_hl(rs[r], h, lo2);
      const int idx = orow * 128 + ((cg ^ (orow & 15)) << 3) + co;
      Xhi[idx] = h;
      Xlo[idx] = lo2;
    }
  }

  // ---- dec: [16 x 512] @ dec_w(pad32); 8 kc per wave; LDS atomic reduce ----
  barrier_lds();   // H4 visible
  {
    f32x16 dacc = zero16();
    const unsigned short* bh = whi + SEG_DEC + (w * 8) * 512 + l * 8;
    const unsigned short* bl = wlo + SEG_DEC + (w * 8) * 512 + l * 8;
    bf16x8 Bh[2], Bl[2];
    Bh[0] = *(const bf16x8*)(bh);
    Bl[0] = *(const bf16x8*)(bl);
#pragma unroll
    for (int kq = 0; kq < 8; ++kq) {
      const int cur = kq & 1;
      if (kq < 7) {
        Bh[cur ^ 1] = *(const bf16x8*)(bh + (kq + 1) * 512);
        Bl[cur ^ 1] = *(const bf16x8*)(bl + (kq + 1) * 512);
      }
      const int kcg = w * 8 + kq;          // global k-chunk 0..31
      const int k0 = kcg * 16 + lh * 8;    // 0..504
      const int agent = k0 >> 7;
      const int d0 = k0 & 127;
      const int row = (lr & 15) * 4 + agent;   // batch (dup for lr>=16), agent
      const int xi = xswz(row, d0 >> 3);
      const bf16x8 ah = *(const bf16x8*)&Xhi[xi];
      const bf16x8 al = *(const bf16x8*)&Xlo[xi];
      dacc = MFMA(ah, Bh[cur], dacc);
      dacc = MFMA(al, Bh[cur], dacc);
      dacc = MFMA(ah, Bl[cur], dacc);
    }
    if (lr < 16) {   // cols 16..31 are zero-pad; D rows 16..31 are dup batches
#pragma unroll
      for (int r = 0; r < 8; ++r) {
        const int batch = (r & 3) + 8 * (r >> 2) + 4 * lh;   // 0..15
        atomicAdd(&Pbuf[batch * 16 + lr], dacc[r]);
      }
    }
  }
  barrier_lds();   // partials complete

  // ---- + bias, softmax over 16 actions, coalesced store ----
  {
    const int c = tid & 15;
    float v = Pbuf[tid] + dec_b[c];
    float m = v;
#pragma unroll
    for (int mk = 1; mk < 16; mk <<= 1) m = fmaxf(m, __shfl_xor(m, mk, 16));
    const float e = __expf(v - m);
    float s = e;
#pragma unroll
    for (int mk = 1; mk < 16; mk <<= 1) s += __shfl_xor(s, mk, 16);
    out[(long)blockIdx.x * 256 + tid] = e / s;
  }
}

// ---------------------------------------------------------------------------
extern "C" void kernel_launch(void* const* d_in, const int* in_sizes, int n_in,
                              void* d_out, int out_size, void* d_ws, size_t ws_size,
                              hipStream_t stream) {
  (void)n_in; (void)out_size; (void)ws_size;  // needs ws_size >= 425,984 B
  const float* O     = (const float*)d_in[0];
  const float* enc_w = (const float*)d_in[1];
  const float* enc_b = (const float*)d_in[2];
  const float* fc1_w = (const float*)d_in[3];
  const float* fc1_b = (const float*)d_in[4];
  const float* fc2_w = (const float*)d_in[5];
  const float* fc2_b = (const float*)d_in[6];
  const float* fc3_w = (const float*)d_in[7];
  const float* fc3_b = (const float*)d_in[8];
  const float* cl4_w = (const float*)d_in[9];
  const float* cl4_b = (const float*)d_in[10];
  const float* dec_w = (const float*)d_in[11];
  const float* dec_b = (const float*)d_in[12];
  unsigned short* wsb = (unsigned short*)d_ws;

  prep_weights<<<(WS_HALF + 255) / 256, 256, 0, stream>>>(enc_w, fc1_w, fc2_w, fc3_w,
                                                          cl4_w, dec_w, wsb);
  const int rows   = in_sizes[0] / 64;   // B*A = 262144
  const int blocks = rows / 64;          // 4096
  commnet_fwd<<<blocks, 256, 0, stream>>>(O, enc_b, fc1_b, fc2_b, fc3_b, cl4_b,
                                          dec_b, wsb, (float*)d_out);
}

// Round 7
// 176.509 us; speedup vs baseline: 1.8429x; 1.2321x over previous
//
#include <hip/hip_runtime.h>
#include <stdint.h>

// ---------------------------------------------------------------------------
// CommNetActor fused forward v7 — bf16x3 split-precision MFMA (gfx950).
//
//  R6 post-mortem: spills ~gone, FETCH ideal, but MfmaUtil 28% with ~100us
//  unexplained == the 2x-duplicated L2 weight stream of quadrant ownership
//  (each 64-col wave pair refetches B per 32-row band; 3.4 GB total).
//
//  v7 = v6 with v2-style DISTINCT col ownership + deeper prefetch:
//   - wave w owns cols w*32..+31, reads ALL 64 rows (acc0 rows 0-31, acc1
//     rows 32-63): B fetched exactly once per block -> L2 1.7 GB (~49us).
//     A-LDS duplication 4x (~+30us at 69 TB/s) -- accepted, sub-dominant.
//   - 2 B streams (hi/lo) instead of 4 -> depth-3 prefetch (covers ~100cyc
//     of ~200cyc L2 latency) still fewer VGPRs than v6.
//   - cl4 fused comm kept (T = sum of 4 consecutive acc regs), split into
//     two row-band passes so register peak fits the (256,3) budget.
//   - LDS 33.8 KB (Xhi 16K + Xlo 16K + Pbuf 1K) -> 3 blocks/CU (reg-limited).
//   - dec: K=512 split 8 kc/wave, partials via LDS atomicAdd.
//  MFMA 32x32x16_bf16, D layout col=lane&31, row=(r&3)+8*(r>>2)+4*(lane>>5).
// ---------------------------------------------------------------------------

typedef __attribute__((ext_vector_type(4)))  float f32x4;
typedef __attribute__((ext_vector_type(16))) float f32x16;
typedef __attribute__((ext_vector_type(8)))  short bf16x8;
typedef __attribute__((ext_vector_type(4)))  short bf16x4;

#define WS_HALF 106496
#define SEG_ENC 0
#define SEG_FC1 8192
#define SEG_FC2 24576
#define SEG_FC3 40960
#define SEG_W1  57344
#define SEG_W2  73728
#define SEG_DEC 90112

#define MFMA(a, b, c) __builtin_amdgcn_mfma_f32_32x32x16_bf16((a), (b), (c), 0, 0, 0)

__device__ __forceinline__ unsigned short bf16_rn(float f) {
  union { float f; uint32_t u; } v; v.f = f;
  uint32_t u = v.u;
  return (unsigned short)((u + 0x7FFFu + ((u >> 16) & 1u)) >> 16);
}
__device__ __forceinline__ float bf16_f32(unsigned short h) {
  union { uint32_t u; float f; } v; v.u = ((uint32_t)h) << 16;
  return v.f;
}
// hi = round-nearest bf16; lo = truncated bf16 of residual.
__device__ __forceinline__ void split_hl(float v, short& h, short& l) {
  unsigned short hh = bf16_rn(v);
  h = (short)hh;
  union { float f; uint32_t u; } c; c.f = v - bf16_f32(hh);
  l = (short)(c.u >> 16);
}
__device__ __forceinline__ f32x16 zero16() {
  f32x16 v;
#pragma unroll
  for (int i = 0; i < 16; ++i) v[i] = 0.0f;
  return v;
}
// swizzled bf16 index: pitch 128, 16B groups XOR'd by row&15
__device__ __forceinline__ int xswz(int row, int g) {
  return row * 128 + ((g ^ (row & 15)) << 3);
}
// barrier draining LDS ops only — register-bound global loads stay in flight
__device__ __forceinline__ void barrier_lds() {
  asm volatile("s_waitcnt lgkmcnt(0)\n\ts_barrier" ::: "memory");
}

// ---------------------------------------------------------------------------
// Weight prep (layout unchanged): fragment f = kc*nbN + nb,
//   value = W[kc*16 + (lane>>5)*8 + j][nb*32 + (lane&31)]
// cl4 split into W1 = Wtop - 0.25*Wbot and W2 = 0.25*Wbot. dec padded N16->32.
// ---------------------------------------------------------------------------
__global__ void prep_weights(const float* __restrict__ enc_w, const float* __restrict__ fc1_w,
                             const float* __restrict__ fc2_w, const float* __restrict__ fc3_w,
                             const float* __restrict__ cl4_w, const float* __restrict__ dec_w,
                             unsigned short* __restrict__ ws) {
  int idx = blockIdx.x * 256 + threadIdx.x;
  if (idx >= WS_HALF) return;
  const float* W; int base, N, nbN, mode;
  if      (idx <  8192) { W = enc_w; base = SEG_ENC; N = 128; nbN = 4; mode = 0; }
  else if (idx < 24576) { W = fc1_w; base = SEG_FC1; N = 128; nbN = 4; mode = 0; }
  else if (idx < 40960) { W = fc2_w; base = SEG_FC2; N = 128; nbN = 4; mode = 0; }
  else if (idx < 57344) { W = fc3_w; base = SEG_FC3; N = 128; nbN = 4; mode = 0; }
  else if (idx < 73728) { W = cl4_w; base = SEG_W1;  N = 128; nbN = 4; mode = 1; }
  else if (idx < 90112) { W = cl4_w; base = SEG_W2;  N = 128; nbN = 4; mode = 2; }
  else                  { W = dec_w; base = SEG_DEC; N = 16;  nbN = 1; mode = 0; }
  int local = idx - base;
  int j    = local & 7;
  int lane = (local >> 3) & 63;
  int frag = local >> 9;
  int nb = frag % nbN;
  int kc = frag / nbN;
  int k = kc * 16 + ((lane >> 5) << 3) + j;
  int n = nb * 32 + (lane & 31);
  float wv;
  if (mode == 0)      wv = (n < N) ? W[k * N + n] : 0.0f;
  else if (mode == 1) wv = W[k * 128 + n] - 0.25f * W[(k + 128) * 128 + n];
  else                wv = 0.25f * W[(k + 128) * 128 + n];
  unsigned short hi = bf16_rn(wv);
  ws[idx]           = hi;
  ws[WS_HALF + idx] = bf16_rn(wv - bf16_f32(hi));
}

// ---------------------------------------------------------------------------
// Standard layer: X[64][K] @ W[K][128] + b, act, in-place into Xhi/Xlo.
// Wave w owns cols w*32..+31 (distinct B, 1x per block), reads all 64 rows
// (acc0 rows 0-31, acc1 rows 32-63). B depth-3 prefetch from L2.
// ---------------------------------------------------------------------------
template <int KC, int ACT>
__device__ __forceinline__ void layer_std(short* __restrict__ Xhi, short* __restrict__ Xlo,
                                          const unsigned short* __restrict__ whi,
                                          const unsigned short* __restrict__ wlo,
                                          const float* __restrict__ bias,
                                          int lr, int lh, int w) {
  const int l = lh * 32 + lr;
  f32x16 acc0 = zero16(), acc1 = zero16();
  const unsigned short* bh = whi + w * 512 + l * 8;
  const unsigned short* bl = wlo + w * 512 + l * 8;
  bf16x8 Bh[3], Bl[3];
  Bh[0] = *(const bf16x8*)(bh);
  Bl[0] = *(const bf16x8*)(bl);
  if (KC > 1) {
    Bh[1] = *(const bf16x8*)(bh + 2048);
    Bl[1] = *(const bf16x8*)(bl + 2048);
  }
  barrier_lds();   // X from previous phase visible (B loads stay in flight)
#pragma unroll
  for (int kc = 0; kc < KC; ++kc) {
    const int cur = kc % 3;
    if (kc + 2 < KC) {
      const int nx = (kc + 2) % 3;
      Bh[nx] = *(const bf16x8*)(bh + (kc + 2) * 2048);
      Bl[nx] = *(const bf16x8*)(bl + (kc + 2) * 2048);
    }
    const int g = kc * 2 + lh;
    const int xi0 = xswz(lr, g), xi1 = xswz(lr + 32, g);
    const bf16x8 ah0 = *(const bf16x8*)&Xhi[xi0];
    const bf16x8 al0 = *(const bf16x8*)&Xlo[xi0];
    const bf16x8 ah1 = *(const bf16x8*)&Xhi[xi1];
    const bf16x8 al1 = *(const bf16x8*)&Xlo[xi1];
    acc0 = MFMA(ah0, Bh[cur], acc0);
    acc1 = MFMA(ah1, Bh[cur], acc1);
    acc0 = MFMA(al0, Bh[cur], acc0);
    acc1 = MFMA(al1, Bh[cur], acc1);
    acc0 = MFMA(ah0, Bl[cur], acc0);
    acc1 = MFMA(ah1, Bl[cur], acc1);
  }
  barrier_lds();   // all waves done reading X -> in-place write safe
  const int col = w * 32 + lr;
  const float bv = bias[col];
  const int cg = col >> 3, co = col & 7;
#pragma unroll
  for (int mb = 0; mb < 2; ++mb) {
    const f32x16 a = mb ? acc1 : acc0;
#pragma unroll
    for (int r = 0; r < 16; ++r) {
      const int orow = mb * 32 + (r & 3) + 8 * (r >> 2) + 4 * lh;
      float v = a[r] + bv;
      if (ACT == 0)      v = 1.0f / (1.0f + __expf(-v));  // sigmoid
      else if (ACT == 1) v = fmaxf(v, 0.0f);              // relu
      short h, lo2;
      split_hl(v, h, lo2);
      const int idx = orow * 128 + ((cg ^ (orow & 15)) << 3) + co;
      Xhi[idx] = h;
      Xlo[idx] = lo2;
    }
  }
}

// ---------------------------------------------------------------------------
// cl4 band MB (rows MB*32..+31, cols w*32..+31): a1 = H3@W1, a2 = H3@W2.
// H4 = a1[r] + T_q + b, T_q = sum of a2[4q..4q+3] (4 agent rows of one batch
// sit in 4 consecutive accumulator regs of the same lane).
// ---------------------------------------------------------------------------
template <int MB>
__device__ __forceinline__ f32x16 cl4_band(const short* __restrict__ Xhi,
                                           const short* __restrict__ Xlo,
                                           const unsigned short* __restrict__ whi,
                                           const unsigned short* __restrict__ wlo,
                                           const float* __restrict__ cl4_b,
                                           int lr, int lh, int w) {
  const int l = lh * 32 + lr;
  f32x16 a1 = zero16(), a2 = zero16();
  const unsigned short* b1h = whi + SEG_W1 + w * 512 + l * 8;
  const unsigned short* b1l = wlo + SEG_W1 + w * 512 + l * 8;
  const unsigned short* b2h = whi + SEG_W2 + w * 512 + l * 8;
  const unsigned short* b2l = wlo + SEG_W2 + w * 512 + l * 8;
  bf16x8 B1h[2], B1l[2], B2h[2], B2l[2];
  B1h[0] = *(const bf16x8*)(b1h);
  B1l[0] = *(const bf16x8*)(b1l);
  B2h[0] = *(const bf16x8*)(b2h);
  B2l[0] = *(const bf16x8*)(b2l);
#pragma unroll
  for (int kc = 0; kc < 8; ++kc) {
    const int cur = kc & 1;
    if (kc < 7) {
      const int nx = cur ^ 1;
      B1h[nx] = *(const bf16x8*)(b1h + (kc + 1) * 2048);
      B1l[nx] = *(const bf16x8*)(b1l + (kc + 1) * 2048);
      B2h[nx] = *(const bf16x8*)(b2h + (kc + 1) * 2048);
      B2l[nx] = *(const bf16x8*)(b2l + (kc + 1) * 2048);
    }
    const int xi = xswz(MB * 32 + lr, kc * 2 + lh);
    const bf16x8 ah = *(const bf16x8*)&Xhi[xi];
    const bf16x8 al = *(const bf16x8*)&Xlo[xi];
    a1 = MFMA(ah, B1h[cur], a1);
    a2 = MFMA(ah, B2h[cur], a2);
    a1 = MFMA(al, B1h[cur], a1);
    a2 = MFMA(al, B2h[cur], a2);
    a1 = MFMA(ah, B1l[cur], a1);
    a2 = MFMA(ah, B2l[cur], a2);
  }
  const float bv = cl4_b[w * 32 + lr];
  f32x16 res;
#pragma unroll
  for (int q = 0; q < 4; ++q) {
    const float T = (a2[4 * q] + a2[4 * q + 1]) + (a2[4 * q + 2] + a2[4 * q + 3]);
#pragma unroll
    for (int rr = 0; rr < 4; ++rr) res[4 * q + rr] = a1[4 * q + rr] + T + bv;
  }
  return res;
}

// ---------------------------------------------------------------------------
__global__ __launch_bounds__(256, 3)
void commnet_fwd(const float* __restrict__ O,
                 const float* __restrict__ enc_b, const float* __restrict__ fc1_b,
                 const float* __restrict__ fc2_b, const float* __restrict__ fc3_b,
                 const float* __restrict__ cl4_b, const float* __restrict__ dec_b,
                 const unsigned short* __restrict__ ws, float* __restrict__ out) {
  __shared__ __attribute__((aligned(16))) short Xhi[64 * 128];  // 16 KB
  __shared__ __attribute__((aligned(16))) short Xlo[64 * 128];  // 16 KB
  __shared__ __attribute__((aligned(16))) float Pbuf[256];      //  1 KB

  const int tid = threadIdx.x;
  const int l = tid & 63, w = tid >> 6;
  const int lr = l & 31, lh = l >> 5;

  Pbuf[tid] = 0.0f;   // dec partial accumulator (one element per thread)

  // ---- stage O [64 x 64] f32 -> split -> swizzled Xhi/Xlo groups 0..7 ----
  {
    const f32x4* Og = (const f32x4*)(O + (long)blockIdx.x * 4096);
#pragma unroll
    for (int it = 0; it < 4; ++it) {
      const int i = it * 256 + tid;       // 0..1023
      const int row = i >> 4;
      const int c4 = (i & 15) << 2;
      f32x4 v = Og[i];
      bf16x4 hv, lv;
#pragma unroll
      for (int j = 0; j < 4; ++j) {
        short hh, ll;
        split_hl(v[j], hh, ll);
        hv[j] = hh; lv[j] = ll;
      }
      const int bi = row * 128 + (((c4 >> 3) ^ (row & 15)) << 3) + (c4 & 7);
      *(bf16x4*)&Xhi[bi] = hv;
      *(bf16x4*)&Xlo[bi] = lv;
    }
  }

  const unsigned short* whi = ws;
  const unsigned short* wlo = ws + WS_HALF;

  layer_std<4, 0>(Xhi, Xlo, whi + SEG_ENC, wlo + SEG_ENC, enc_b, lr, lh, w);
  layer_std<8, 1>(Xhi, Xlo, whi + SEG_FC1, wlo + SEG_FC1, fc1_b, lr, lh, w);
  layer_std<8, 1>(Xhi, Xlo, whi + SEG_FC2, wlo + SEG_FC2, fc2_b, lr, lh, w);
  layer_std<8, 1>(Xhi, Xlo, whi + SEG_FC3, wlo + SEG_FC3, fc3_b, lr, lh, w);

  // ---- cl4: two row-band passes, results in regs, single write phase ----
  barrier_lds();   // H3 (fc3 epilogue) visible
  const f32x16 res0 = cl4_band<0>(Xhi, Xlo, whi, wlo, cl4_b, lr, lh, w);
  const f32x16 res1 = cl4_band<1>(Xhi, Xlo, whi, wlo, cl4_b, lr, lh, w);
  barrier_lds();   // all H3 reads done -> in-place write safe
  {
    const int col = w * 32 + lr;
    const int cg = col >> 3, co = col & 7;
#pragma unroll
    for (int mb = 0; mb < 2; ++mb) {
      const f32x16 rs = mb ? res1 : res0;
#pragma unroll
      for (int r = 0; r < 16; ++r) {
        const int orow = mb * 32 + (r & 3) + 8 * (r >> 2) + 4 * lh;
        short h, lo2;
        split_hl(rs[r], h, lo2);
        const int idx = orow * 128 + ((cg ^ (orow & 15)) << 3) + co;
        Xhi[idx] = h;
        Xlo[idx] = lo2;
      }
    }
  }

  // ---- dec: [16 x 512] @ dec_w(pad32); 8 kc per wave; LDS atomic reduce ----
  barrier_lds();   // H4 visible
  {
    f32x16 dacc = zero16();
    const unsigned short* bh = whi + SEG_DEC + (w * 8) * 512 + l * 8;
    const unsigned short* bl = wlo + SEG_DEC + (w * 8) * 512 + l * 8;
    bf16x8 Bh[2], Bl[2];
    Bh[0] = *(const bf16x8*)(bh);
    Bl[0] = *(const bf16x8*)(bl);
#pragma unroll
    for (int kq = 0; kq < 8; ++kq) {
      const int cur = kq & 1;
      if (kq < 7) {
        Bh[cur ^ 1] = *(const bf16x8*)(bh + (kq + 1) * 512);
        Bl[cur ^ 1] = *(const bf16x8*)(bl + (kq + 1) * 512);
      }
      const int kcg = w * 8 + kq;          // global k-chunk 0..31
      const int k0 = kcg * 16 + lh * 8;    // 0..504
      const int agent = k0 >> 7;
      const int d0 = k0 & 127;
      const int row = (lr & 15) * 4 + agent;   // batch (dup for lr>=16), agent
      const int xi = xswz(row, d0 >> 3);
      const bf16x8 ah = *(const bf16x8*)&Xhi[xi];
      const bf16x8 al = *(const bf16x8*)&Xlo[xi];
      dacc = MFMA(ah, Bh[cur], dacc);
      dacc = MFMA(al, Bh[cur], dacc);
      dacc = MFMA(ah, Bl[cur], dacc);
    }
    if (lr < 16) {   // cols 16..31 are zero-pad; D rows 16..31 are dup batches
#pragma unroll
      for (int r = 0; r < 8; ++r) {
        const int batch = (r & 3) + 8 * (r >> 2) + 4 * lh;   // 0..15
        atomicAdd(&Pbuf[batch * 16 + lr], dacc[r]);
      }
    }
  }
  barrier_lds();   // partials complete

  // ---- + bias, softmax over 16 actions, coalesced store ----
  {
    const int c = tid & 15;
    float v = Pbuf[tid] + dec_b[c];
    float m = v;
#pragma unroll
    for (int mk = 1; mk < 16; mk <<= 1) m = fmaxf(m, __shfl_xor(m, mk, 16));
    const float e = __expf(v - m);
    float s = e;
#pragma unroll
    for (int mk = 1; mk < 16; mk <<= 1) s += __shfl_xor(s, mk, 16);
    out[(long)blockIdx.x * 256 + tid] = e / s;
  }
}

// ---------------------------------------------------------------------------
extern "C" void kernel_launch(void* const* d_in, const int* in_sizes, int n_in,
                              void* d_out, int out_size, void* d_ws, size_t ws_size,
                              hipStream_t stream) {
  (void)n_in; (void)out_size; (void)ws_size;  // needs ws_size >= 425,984 B
  const float* O     = (const float*)d_in[0];
  const float* enc_w = (const float*)d_in[1];
  const float* enc_b = (const float*)d_in[2];
  const float* fc1_w = (const float*)d_in[3];
  const float* fc1_b = (const float*)d_in[4];
  const float* fc2_w = (const float*)d_in[5];
  const float* fc2_b = (const float*)d_in[6];
  const float* fc3_w = (const float*)d_in[7];
  const float* fc3_b = (const float*)d_in[8];
  const float* cl4_w = (const float*)d_in[9];
  const float* cl4_b = (const float*)d_in[10];
  const float* dec_w = (const float*)d_in[11];
  const float* dec_b = (const float*)d_in[12];
  unsigned short* wsb = (unsigned short*)d_ws;

  prep_weights<<<(WS_HALF + 255) / 256, 256, 0, stream>>>(enc_w, fc1_w, fc2_w, fc3_w,
                                                          cl4_w, dec_w, wsb);
  const int rows   = in_sizes[0] / 64;   // B*A = 262144
  const int blocks = rows / 64;          // 4096
  commnet_fwd<<<blocks, 256, 0, stream>>>(O, enc_b, fc1_b, fc2_b, fc3_b, cl4_b,
                                          dec_b, wsb, (float*)d_out);
}